// Round 5
// baseline (381.344 us; speedup 1.0000x reference)
//
#include <hip/hip_runtime.h>
#include <hip/hip_bf16.h>
#include <cstdint>

typedef unsigned short u16;
typedef __attribute__((ext_vector_type(8))) short bf16x8;
typedef __attribute__((ext_vector_type(4))) float f32x4;
typedef __attribute__((ext_vector_type(16))) float f32x16;

#define B_ROWS 16384
#define N_HID  1024
#define K_DIM  6144
#define EMB    128
#define N_WORD 100000
#define N_TAG  48
#define N_DEP  40
#define NTILES 96
#define NITER  48

__device__ __forceinline__ u16 f2bf(float x) {
  union { float f; uint32_t u; } v; v.f = x;
  uint32_t r = v.u + 0x7fffu + ((v.u >> 16) & 1u);
  return (u16)(r >> 16);
}

__device__ __forceinline__ void gload_lds16(const void* g, void* l) {
  __builtin_amdgcn_global_load_lds(
      (const __attribute__((address_space(1))) void*)g,
      (__attribute__((address_space(3))) void*)l, 16, 0, 0);
}

#define SBAR do { \
  __builtin_amdgcn_sched_barrier(0); \
  asm volatile("" ::: "memory"); \
  __builtin_amdgcn_s_barrier(); \
  asm volatile("" ::: "memory"); \
  __builtin_amdgcn_sched_barrier(0); \
} while (0)

__global__ void init_out_kernel(float* __restrict__ out, const float* __restrict__ b_o) {
  int i = blockIdx.x * blockDim.x + threadIdx.x;
  if (i < B_ROWS * 3) out[i] = b_o[i % 3];
}

__global__ void transpose_wh_kernel(const float* __restrict__ Wh, u16* __restrict__ Wt) {
  __shared__ float tile[32][33];
  int k0 = blockIdx.x * 32, n0 = blockIdx.y * 32;
  int tx = threadIdx.x & 31, ty = threadIdx.x >> 5;
  #pragma unroll
  for (int j = 0; j < 4; ++j)
    tile[ty + j * 8][tx] = Wh[(size_t)(k0 + ty + j * 8) * N_HID + n0 + tx];
  __syncthreads();
  #pragma unroll
  for (int j = 0; j < 4; ++j)
    Wt[(size_t)(n0 + ty + j * 8) * K_DIM + k0 + tx] = f2bf(tile[tx][ty + j * 8]);
}

__global__ void cast_tables_kernel(const float* __restrict__ wordE, const float* __restrict__ tagE,
                                   const float* __restrict__ depE, u16* __restrict__ tblB) {
  const int W8 = N_WORD * EMB / 8, T8 = N_TAG * EMB / 8, D8 = N_DEP * EMB / 8;
  int i = blockIdx.x * blockDim.x + threadIdx.x;
  const float* src; int j;
  if (i < W8)                { src = wordE; j = i; }
  else if (i < W8 + T8)      { src = tagE;  j = i - W8; }
  else if (i < W8 + T8 + D8) { src = depE;  j = i - W8 - T8; }
  else return;
  const float4* s = (const float4*)(src + (size_t)j * 8);
  float4 v0 = s[0], v1 = s[1];
  bf16x8 w;
  w[0] = (short)f2bf(v0.x); w[1] = (short)f2bf(v0.y);
  w[2] = (short)f2bf(v0.z); w[3] = (short)f2bf(v0.w);
  w[4] = (short)f2bf(v1.x); w[5] = (short)f2bf(v1.y);
  w[6] = (short)f2bf(v1.z); w[7] = (short)f2bf(v1.w);
  *(bf16x8*)(tblB + (size_t)i * 8) = w;
}

__global__ void build_offv_kernel(const int* __restrict__ w, const int* __restrict__ t,
                                  const int* __restrict__ d, int* __restrict__ offv) {
  int row = blockIdx.x * 256 + threadIdx.x;
  int f = blockIdx.y;
  if (row >= B_ROWS) return;
  int off;
  if (f < 18)      off = w[row * 18 + f] * EMB;
  else if (f < 36) off = N_WORD * EMB + t[row * 18 + (f - 18)] * EMB;
  else             off = (N_WORD + N_TAG) * EMB + d[row * 12 + (f - 36)] * EMB;
  offv[f * B_ROWS + row] = off;
}

// ---------------- v4: 256x256, 32x32x16 MFMA, frag-prefetch 8-phase pipeline ----------------
__global__ __launch_bounds__(512, 2) void fused_v4_kernel(
    const u16* __restrict__ tblB, const int* __restrict__ offv,
    const u16* __restrict__ Wt,   const float* __restrict__ b_h,
    const float* __restrict__ W_o, float* __restrict__ out) {
  __shared__ u16 As[2][256 * 64];
  __shared__ u16 Bs[2][256 * 64];

  const int tid  = threadIdx.x;
  const int lane = tid & 63;
  const int wid  = tid >> 6;        // 0..7
  const int wr   = wid >> 2;        // 0..1 -> 128-row band
  const int wc   = wid & 3;         // 0..3 -> 64-col band
  const int bn0  = blockIdx.x * 256;
  const int bm0  = blockIdx.y * 256;
  const int l31  = lane & 31, lh = lane >> 5;

  // staging constants
  const int r0 = tid >> 3;          // 0..63
  const int c  = tid & 7;
  const int sc = ((c ^ (r0 & 7)) << 3);
  const u16* Bp[4];
  #pragma unroll
  for (int j = 0; j < 4; ++j)
    Bp[j] = Wt + (size_t)(bn0 + j * 64 + r0) * K_DIM + sc;
  const int ivb = bm0 + r0;

#define DESTA(buf, h, is) ((void*)&As[buf][(h) * 8192 + (is) * 4096 + wid * 512])
#define DESTB(buf, h, is) ((void*)&Bs[buf][(h) * 8192 + (is) * 4096 + wid * 512])
#define STAGE_B2(buf, h, t) do { \
    gload_lds16(Bp[2 * (h)] + (size_t)(t) * 64, DESTB(buf, h, 0)); \
    gload_lds16(Bp[2 * (h) + 1] + (size_t)(t) * 64, DESTB(buf, h, 1)); } while (0)
#define STAGE_A2(buf, h, e0) do { \
    gload_lds16(tblB + (size_t)oA[2 * (h)] + (e0) + sc, DESTA(buf, h, 0)); \
    gload_lds16(tblB + (size_t)oA[2 * (h) + 1] + (e0) + sc, DESTA(buf, h, 1)); } while (0)

  // fragment-read constants (32x32x16: row = lane&31, k = (lane>>5)*8 + j)
  const u16* aB[2] = { &As[0][(wr * 128 + l31) * 64], &As[1][(wr * 128 + l31) * 64] };
  const u16* bB[2] = { &Bs[0][(wc * 64  + l31) * 64], &Bs[1][(wc * 64  + l31) * 64] };
  int sch[4];
  #pragma unroll
  for (int ks = 0; ks < 4; ++ks) sch[ks] = (((ks * 2 + lh) ^ (lane & 7)) << 3);

#define RD(Aset, Bset, buf, ks) do { \
    _Pragma("unroll") for (int mf = 0; mf < 4; ++mf) \
      Aset[mf] = *(const bf16x8*)(aB[buf] + mf * 2048 + sch[ks]); \
    _Pragma("unroll") for (int nf = 0; nf < 2; ++nf) \
      Bset[nf] = *(const bf16x8*)(bB[buf] + nf * 2048 + sch[ks]); } while (0)

#define MM(Aset, Bset) do { \
    __builtin_amdgcn_s_setprio(1); \
    _Pragma("unroll") for (int mf = 0; mf < 4; ++mf) \
      _Pragma("unroll") for (int nf = 0; nf < 2; ++nf) \
        acc[mf][nf] = __builtin_amdgcn_mfma_f32_32x32x16_bf16(Aset[mf], Bset[nf], acc[mf][nf], 0, 0, 0); \
    __builtin_amdgcn_s_setprio(0); } while (0)

  f32x16 acc[4][2] = {};
  int oA[4];
  bf16x8 A0[4], A1[4], B0[2], B1[2];

  // ---- prologue: stage tile0 (A+B -> buf0), ids f=0; publish; read ks0 ----
  STAGE_B2(0, 0, 0); STAGE_B2(0, 1, 0);
  #pragma unroll
  for (int j = 0; j < 4; ++j) oA[j] = offv[ivb + j * 64];
  STAGE_A2(0, 0, 0); STAGE_A2(0, 1, 0);
  asm volatile("s_waitcnt vmcnt(0)" ::: "memory");
  SBAR;
  RD(A0, B0, 0, 0);

  #pragma unroll 1
  for (int i = 0; i < NITER; ++i) {
    const int T = 2 * i;
    const bool more = (i + 1 < NITER);
    // ph1: read buf0.ks1 -> set1; stage A(T+1,h0)+B(T+1,h0) -> buf1; MFMA set0 (ks0)
    RD(A1, B1, 0, 1);
    STAGE_A2(1, 0, 64); STAGE_B2(1, 0, T + 1);
    SBAR;
    MM(A0, B0);
    SBAR;
    // ph2: read ks2 -> set0; stage A(T+1,h1)+B(T+1,h1); MFMA set1 (ks1)
    RD(A0, B0, 0, 2);
    STAGE_A2(1, 1, 64); STAGE_B2(1, 1, T + 1);
    SBAR;
    MM(A1, B1);
    SBAR;
    // ph3: ids f=i+1; read ks3 -> set1; MFMA set0 (ks2)
    if (more) {
      const int* ov = offv + (i + 1) * B_ROWS + ivb;
      #pragma unroll
      for (int j = 0; j < 4; ++j) oA[j] = ov[j * 64];
    }
    RD(A1, B1, 0, 3);
    SBAR;
    MM(A0, B0);
    SBAR;
    // ph4: GATE T+1 staged; publish; read buf1.ks0 -> set0 (post-barrier!); MFMA set1 (ks3)
    if (i == NITER - 1) { asm volatile("s_waitcnt vmcnt(0)" ::: "memory"); }
    else                { asm volatile("s_waitcnt vmcnt(4)" ::: "memory"); }
    SBAR;
    RD(A0, B0, 1, 0);
    MM(A1, B1);
    SBAR;
    // ph5: read buf1.ks1 -> set1; stage A(T+2,h0)+B(T+2,h0) -> buf0; MFMA set0 (buf1.ks0)
    RD(A1, B1, 1, 1);
    if (more) { STAGE_A2(0, 0, 0); STAGE_B2(0, 0, T + 2); }
    SBAR;
    MM(A0, B0);
    SBAR;
    // ph6: read ks2 -> set0; stage A(T+2,h1)+B(T+2,h1); MFMA set1 (ks1)
    RD(A0, B0, 1, 2);
    if (more) { STAGE_A2(0, 1, 0); STAGE_B2(0, 1, T + 2); }
    SBAR;
    MM(A1, B1);
    SBAR;
    // ph7: read ks3 -> set1; MFMA set0 (ks2)
    RD(A1, B1, 1, 3);
    SBAR;
    MM(A0, B0);
    SBAR;
    // ph8: GATE T+2 staged; publish; read next buf0.ks0 -> set0 (post-barrier); MFMA set1 (ks3)
    if (more) { asm volatile("s_waitcnt vmcnt(0)" ::: "memory"); }
    SBAR;
    if (more) RD(A0, B0, 0, 0);
    MM(A1, B1);
    SBAR;
  }

  // ---- epilogue: h = relu(acc + b_h); out += h @ W_o ----
  // 32x32 C/D: col = lane&31, row = (reg&3) + 8*(reg>>2) + 4*(lane>>5)
  float bh[2], wo[2][3];
  #pragma unroll
  for (int nf = 0; nf < 2; ++nf) {
    int j = bn0 + wc * 64 + nf * 32 + l31;
    bh[nf] = b_h[j];
    wo[nf][0] = W_o[j * 3 + 0]; wo[nf][1] = W_o[j * 3 + 1]; wo[nf][2] = W_o[j * 3 + 2];
  }
  #pragma unroll
  for (int mf = 0; mf < 4; ++mf) {
    #pragma unroll
    for (int reg = 0; reg < 16; ++reg) {
      float p0 = 0.f, p1 = 0.f, p2 = 0.f;
      #pragma unroll
      for (int nf = 0; nf < 2; ++nf) {
        float h = acc[mf][nf][reg] + bh[nf];
        h = fmaxf(h, 0.f);
        p0 += h * wo[nf][0]; p1 += h * wo[nf][1]; p2 += h * wo[nf][2];
      }
      #pragma unroll
      for (int mask = 1; mask < 32; mask <<= 1) {
        p0 += __shfl_xor(p0, mask);
        p1 += __shfl_xor(p1, mask);
        p2 += __shfl_xor(p2, mask);
      }
      if (l31 == 0) {
        int row = bm0 + wr * 128 + mf * 32 + (reg & 3) + 8 * (reg >> 2) + 4 * lh;
        atomicAdd(&out[row * 3 + 0], p0);
        atomicAdd(&out[row * 3 + 1], p1);
        atomicAdd(&out[row * 3 + 2], p2);
      }
    }
  }
#undef DESTA
#undef DESTB
#undef STAGE_B2
#undef STAGE_A2
#undef RD
#undef MM
}

// ---------------- v2 fallback (R3-proven): 128x128, 2-barrier loop ----------------
__global__ __launch_bounds__(256, 4) void fused_v2_kernel(
    const int* __restrict__ word_ids, const int* __restrict__ tag_ids,
    const int* __restrict__ dep_ids,  const u16* __restrict__ tblB,
    const u16* __restrict__ Wt,       const float* __restrict__ b_h,
    const float* __restrict__ W_o,    float* __restrict__ out) {
  __shared__ u16 As2[128 * 64];
  __shared__ u16 Bs2[128 * 64];
  const int tid  = threadIdx.x;
  const int lane = tid & 63;
  const int wid  = tid >> 6;
  const int wr   = wid >> 1, wc = wid & 1;
  const int bm0  = blockIdx.y * 128;
  const int bn0  = blockIdx.x * 128;
  f32x4 acc[4][4] = {};

  for (int kt = 0; kt < K_DIM / 64; ++kt) {
    __syncthreads();
    {
      int f = kt >> 1, e0 = (kt & 1) << 6;
      const int* ids; int nf, fl; size_t tb;
      if (f < 18)      { ids = word_ids; nf = 18; fl = f;      tb = 0; }
      else if (f < 36) { ids = tag_ids;  nf = 18; fl = f - 18; tb = (size_t)N_WORD * EMB; }
      else             { ids = dep_ids;  nf = 12; fl = f - 36; tb = (size_t)(N_WORD + N_TAG) * EMB; }
      #pragma unroll
      for (int it = 0; it < 4; ++it) {
        int cidx = wid * 256 + it * 64 + lane;
        int r = cidx >> 3, cc = cidx & 7;
        int id = ids[(bm0 + r) * nf + fl];
        const u16* src = tblB + tb + (size_t)id * EMB + e0 + ((cc ^ (r & 7)) << 3);
        gload_lds16(src, &As2[(wid * 256 + it * 64) * 8]);
      }
    }
    #pragma unroll
    for (int it = 0; it < 4; ++it) {
      int cidx = wid * 256 + it * 64 + lane;
      int rn = cidx >> 3, cc = cidx & 7;
      const u16* src = Wt + (size_t)(bn0 + rn) * K_DIM + kt * 64 + ((cc ^ (rn & 7)) << 3);
      gload_lds16(src, &Bs2[(wid * 256 + it * 64) * 8]);
    }
    __syncthreads();
    const int l15 = lane & 15, ca = lane >> 4;
    #pragma unroll
    for (int ks = 0; ks < 2; ++ks) {
      bf16x8 a[4], b[4];
      #pragma unroll
      for (int m = 0; m < 4; ++m) {
        int ra = wr * 64 + m * 16 + l15;
        int ch = (ca + ks * 4) ^ (ra & 7);
        a[m] = *(const bf16x8*)&As2[ra * 64 + ch * 8];
      }
      #pragma unroll
      for (int n = 0; n < 4; ++n) {
        int rb = wc * 64 + n * 16 + l15;
        int ch = (ca + ks * 4) ^ (rb & 7);
        b[n] = *(const bf16x8*)&Bs2[rb * 64 + ch * 8];
      }
      #pragma unroll
      for (int m = 0; m < 4; ++m)
        #pragma unroll
        for (int n = 0; n < 4; ++n)
          acc[m][n] = __builtin_amdgcn_mfma_f32_16x16x32_bf16(a[m], b[n], acc[m][n], 0, 0, 0);
    }
  }

  const int l15 = lane & 15;
  float bh[4], wo[4][3];
  #pragma unroll
  for (int n = 0; n < 4; ++n) {
    int j = bn0 + wc * 64 + n * 16 + l15;
    bh[n] = b_h[j];
    wo[n][0] = W_o[j * 3 + 0]; wo[n][1] = W_o[j * 3 + 1]; wo[n][2] = W_o[j * 3 + 2];
  }
  #pragma unroll
  for (int m = 0; m < 4; ++m) {
    #pragma unroll
    for (int reg = 0; reg < 4; ++reg) {
      float p0 = 0.f, p1 = 0.f, p2 = 0.f;
      #pragma unroll
      for (int n = 0; n < 4; ++n) {
        float h = acc[m][n][reg] + bh[n];
        h = fmaxf(h, 0.f);
        p0 += h * wo[n][0]; p1 += h * wo[n][1]; p2 += h * wo[n][2];
      }
      #pragma unroll
      for (int mask = 1; mask < 16; mask <<= 1) {
        p0 += __shfl_xor(p0, mask);
        p1 += __shfl_xor(p1, mask);
        p2 += __shfl_xor(p2, mask);
      }
      if (l15 == 0) {
        int row = bm0 + wr * 64 + m * 16 + ((lane >> 4) << 2) + reg;
        atomicAdd(&out[row * 3 + 0], p0);
        atomicAdd(&out[row * 3 + 1], p1);
        atomicAdd(&out[row * 3 + 2], p2);
      }
    }
  }
}

extern "C" void kernel_launch(void* const* d_in, const int* in_sizes, int n_in,
                              void* d_out, int out_size, void* d_ws, size_t ws_size,
                              hipStream_t stream) {
  const int*   word_ids = (const int*)d_in[0];
  const int*   tag_ids  = (const int*)d_in[1];
  const int*   dep_ids  = (const int*)d_in[2];
  const float* wordE    = (const float*)d_in[3];
  const float* tagE     = (const float*)d_in[4];
  const float* depE     = (const float*)d_in[5];
  const float* Wh       = (const float*)d_in[6];
  const float* b_h      = (const float*)d_in[7];
  const float* W_o      = (const float*)d_in[8];
  const float* b_o      = (const float*)d_in[9];
  float*       out      = (float*)d_out;

  const size_t WT_ELEMS   = (size_t)N_HID * K_DIM;
  const size_t TBL_ELEMS  = (size_t)(N_WORD + N_TAG + N_DEP) * EMB;
  const size_t OFFV_ELEMS = (size_t)48 * B_ROWS;
  const size_t NEED_V2 = (WT_ELEMS + TBL_ELEMS) * sizeof(u16);
  const size_t NEED_V4 = NEED_V2 + OFFV_ELEMS * sizeof(int);

  u16* Wt   = (u16*)d_ws;
  u16* tblB = Wt + WT_ELEMS;
  int* offv = (int*)(tblB + TBL_ELEMS);

  init_out_kernel<<<(B_ROWS * 3 + 255) / 256, 256, 0, stream>>>(out, b_o);

  if (d_ws && ws_size >= NEED_V4) {
    transpose_wh_kernel<<<dim3(K_DIM / 32, N_HID / 32), 256, 0, stream>>>(Wh, Wt);
    cast_tables_kernel<<<(int)((TBL_ELEMS / 8 + 255) / 256), 256, 0, stream>>>(wordE, tagE, depE, tblB);
    build_offv_kernel<<<dim3(B_ROWS / 256, 48), 256, 0, stream>>>(word_ids, tag_ids, dep_ids, offv);
    fused_v4_kernel<<<dim3(N_HID / 256, B_ROWS / 256), 512, 0, stream>>>(
        tblB, offv, Wt, b_h, W_o, out);
  } else if (d_ws && ws_size >= NEED_V2) {
    transpose_wh_kernel<<<dim3(K_DIM / 32, N_HID / 32), 256, 0, stream>>>(Wh, Wt);
    cast_tables_kernel<<<(int)((TBL_ELEMS / 8 + 255) / 256), 256, 0, stream>>>(wordE, tagE, depE, tblB);
    fused_v2_kernel<<<dim3(N_HID / 128, B_ROWS / 128), 256, 0, stream>>>(
        word_ids, tag_ids, dep_ids, tblB, Wt, b_h, W_o, out);
  }
}